// Round 4
// baseline (2358.651 us; speedup 1.0000x reference)
//
#include <hip/hip_runtime.h>
#include <math.h>

#define NF 8
#define SS 5
#define DIN 64
#define KSTEP 3
#define BT 32
#define FH_PAD 68             // fS row pad (bank spread)
#define FSTR (SS*FH_PAD)      // 340 (fh filter stride; 340%32=20 -> 8 distinct banks)
#define HOPSTR (NF*FSTR)      // 2720
#define NS_OFF (KSTEP*HOPSTR) // ws: nsqh [3][8][5] after fh

// exp(-(sqf+sqh-2cr)/3.2) = 2^(CC*cr - CS*sqf - CS*sqh)
#define CS 0.45084219902780109f
#define CC 0.90168439805560218f

__device__ __forceinline__ float fexp2(float x) {
#if __has_builtin(__builtin_amdgcn_exp2f)
  return __builtin_amdgcn_exp2f(x);
#else
  return exp2f(x);
#endif
}

__global__ __launch_bounds__(256) void hidden_prep(
    const float* __restrict__ adjs_hidden,
    const float* __restrict__ features_hidden,
    float* __restrict__ ws)
{
  __shared__ float Ah[NF][SS][SS];
  __shared__ float buf[2][NF][SS][DIN];
  const int t = threadIdx.x;

  if (t < NF*SS*SS) ((float*)Ah)[t] = 0.0f;
  for (int i = t; i < NF*SS*DIN; i += 256) ((float*)buf[0])[i] = features_hidden[i];
  __syncthreads();
  if (t < NF*10) {
    const int iu0[10] = {0,0,0,0,1,1,1,2,2,3};
    const int iu1[10] = {1,2,3,4,2,3,4,3,4,4};
    int f = t / 10, k = t % 10;
    float sg = 1.0f / (1.0f + expf(-adjs_hidden[t]));
    Ah[f][iu0[k]][iu1[k]] = sg;
    Ah[f][iu1[k]][iu0[k]] = sg;
  }
  __syncthreads();

  int cur = 0;
  for (int h = 0; h < KSTEP; ++h) {
    // padded fh for this hop: ws[h*HOPSTR + f*FSTR + s*FH_PAD + d]
    for (int i = t; i < NF*SS*DIN; i += 256) {
      int f = i / (SS*DIN), s = (i / DIN) % SS, d = i % DIN;
      ws[h*HOPSTR + f*FSTR + s*FH_PAD + d] = buf[cur][f][s][d];
    }
    // negated, pre-scaled sq_h
    if (t < NF*SS) {
      float acc = 0.0f;
      int f = t / SS, s = t % SS;
      for (int d = 0; d < DIN; ++d) { float v = buf[cur][f][s][d]; acc = fmaf(v, v, acc); }
      ws[NS_OFF + h*NF*SS + t] = -acc * CS;
    }
    if (h + 1 < KSTEP) {
      __syncthreads();
      for (int i = t; i < NF*SS*DIN; i += 256) {
        int f = i / (SS*DIN), s = (i / DIN) % SS, d = i % DIN;
        float acc = 0.0f;
        for (int j = 0; j < SS; ++j) acc = fmaf(Ah[f][s][j], buf[cur][f][j][d], acc);
        buf[cur^1][f][s][d] = acc;
      }
      __syncthreads();
      cur ^= 1;
    }
  }
}

// One barrier total (after fh staging). All other LDS deps are octet-local
// (8 consecutive lanes share one b -> same wave, program order suffices).
__global__ __launch_bounds__(256, 2) void kc_main(
    const float* __restrict__ adjs,
    const float* __restrict__ feature,
    const int* __restrict__ idxs,
    const float* __restrict__ ws,
    float* __restrict__ out,
    int B, int N)
{
  __shared__ float fh[KSTEP*HOPSTR];     // 32640 B, conflict-free padded layout
  __shared__ float nsqh[KSTEP*NF*SS];    // 480 B
  __shared__ float fS[BT][SS][FH_PAD];   // 43520 B
                                         // ~76.6 KB -> 2 blocks/CU

  const int t   = threadIdx.x;
  const int b_i = t >> 3;   // 0..31 (octet = one b)
  const int f_  = t & 7;    // filter / d-slice owner
  const int bg  = blockIdx.x * BT + b_i;
  const bool valid = bg < B;

  // --- cooperative fh + nsqh staging (cross-wave -> the one barrier) ---
  for (int i = t; i < KSTEP*HOPSTR; i += 256) fh[i] = ws[i];
  for (int i = t; i < KSTEP*NF*SS; i += 256) nsqh[i] = ws[NS_OFF + i];

  // --- adj into registers (octet-broadcast loads) ---
  float a[SS*SS];
  #pragma unroll
  for (int k = 0; k < SS*SS; ++k)
    a[k] = valid ? adjs[(size_t)bg*(SS*SS) + k] : 0.0f;

  // --- gather: thread owns d-columns [8f_, 8f_+8) of its b, kept in regs ---
  float fr[SS][8];
  #pragma unroll
  for (int m = 0; m < SS; ++m) {
    int id = valid ? idxs[bg*SS + m] : -1;
    #pragma unroll
    for (int h2 = 0; h2 < 2; ++h2) {
      float4 v = make_float4(0.f, 0.f, 0.f, 0.f);
      if ((unsigned)id < (unsigned)N)
        v = reinterpret_cast<const float4*>(feature)[(size_t)id*16 + f_*2 + h2];
      fr[m][h2*4+0] = v.x; fr[m][h2*4+1] = v.y;
      fr[m][h2*4+2] = v.z; fr[m][h2*4+3] = v.w;
      *reinterpret_cast<float4*>(&fS[b_i][m][f_*8 + h2*4]) = v;
    }
  }

  __syncthreads();  // fh ready (fS is octet-local, already ordered)

  float total[SS][SS];
  #pragma unroll
  for (int m = 0; m < SS; ++m)
    #pragma unroll
    for (int s = 0; s < SS; ++s) total[m][s] = 0.0f;

  #pragma unroll 1
  for (int hop = 0; hop < KSTEP; ++hop) {
    // --- sqf: per-lane partial over own 8 d's, butterfly over octet ---
    float sqf2[SS];
    #pragma unroll
    for (int m = 0; m < SS; ++m) {
      float p = 0.0f;
      #pragma unroll
      for (int dd = 0; dd < 8; ++dd) p = fmaf(fr[m][dd], fr[m][dd], p);
      sqf2[m] = p;
    }
    #pragma unroll
    for (int r = 1; r < 8; r <<= 1)
      #pragma unroll
      for (int m = 0; m < SS; ++m) sqf2[m] += __shfl_xor(sqf2[m], r);
    #pragma unroll
    for (int m = 0; m < SS; ++m) sqf2[m] *= CS;

    // --- cross: cr[m][s] = sum_d f[m][d]*fh[f_][s][d] ---
    float cr[SS][SS];
    #pragma unroll
    for (int m = 0; m < SS; ++m)
      #pragma unroll
      for (int s = 0; s < SS; ++s) cr[m][s] = 0.0f;

    const float* fhh = &fh[hop*HOPSTR + f_*FSTR];
    #pragma unroll
    for (int d4 = 0; d4 < 16; ++d4) {
      float4 fv[SS], hv[SS];
      #pragma unroll
      for (int m = 0; m < SS; ++m)
        fv[m] = *reinterpret_cast<const float4*>(&fS[b_i][m][d4*4]);
      #pragma unroll
      for (int s = 0; s < SS; ++s)
        hv[s] = *reinterpret_cast<const float4*>(&fhh[s*FH_PAD + d4*4]);
      #pragma unroll
      for (int m = 0; m < SS; ++m)
        #pragma unroll
        for (int s = 0; s < SS; ++s) {
          cr[m][s] = fmaf(fv[m].x, hv[s].x, cr[m][s]);
          cr[m][s] = fmaf(fv[m].y, hv[s].y, cr[m][s]);
          cr[m][s] = fmaf(fv[m].z, hv[s].z, cr[m][s]);
          cr[m][s] = fmaf(fv[m].w, hv[s].w, cr[m][s]);
        }
    }

    float nh[SS];
    #pragma unroll
    for (int s = 0; s < SS; ++s) nh[s] = nsqh[hop*NF*SS + f_*SS + s];
    #pragma unroll
    for (int m = 0; m < SS; ++m)
      #pragma unroll
      for (int s = 0; s < SS; ++s) {
        float arg = fmaf(CC, cr[m][s], nh[s] - sqf2[m]);  // <= 0 always
        total[m][s] += fexp2(arg);
      }

    // --- hop update: pure-register fn = adj @ fr, publish to fS ---
    if (hop + 1 < KSTEP) {
      float fn[SS][8];
      #pragma unroll
      for (int m = 0; m < SS; ++m) {
        #pragma unroll
        for (int dd = 0; dd < 8; ++dd) fn[m][dd] = 0.0f;
        #pragma unroll
        for (int j = 0; j < SS; ++j)
          #pragma unroll
          for (int dd = 0; dd < 8; ++dd)
            fn[m][dd] = fmaf(a[m*SS + j], fr[j][dd], fn[m][dd]);
      }
      #pragma unroll
      for (int m = 0; m < SS; ++m) {
        #pragma unroll
        for (int dd = 0; dd < 8; ++dd) fr[m][dd] = fn[m][dd];
        #pragma unroll
        for (int h2 = 0; h2 < 2; ++h2) {
          float4 v = make_float4(fn[m][h2*4+0], fn[m][h2*4+1],
                                 fn[m][h2*4+2], fn[m][h2*4+3]);
          *reinterpret_cast<float4*>(&fS[b_i][m][f_*8 + h2*4]) = v;
        }
      }
    }
  }

  // greedy matching: row 0 -> col 0; rows 1..4 argmax over untaken cols
  float res = total[0][0];
  int taken = 1;
  #pragma unroll
  for (int r = 1; r < SS; ++r) {
    float best = -2.0f; int bi = 0;
    #pragma unroll
    for (int s = 0; s < SS; ++s) {
      float sc = ((taken >> s) & 1) ? -1.0f : total[r][s];
      if (sc > best) { best = sc; bi = s; }
    }
    res += best;
    taken |= (1 << bi);
  }
  if (valid) out[(size_t)bg*NF + f_] = res;
}

extern "C" void kernel_launch(void* const* d_in, const int* in_sizes, int n_in,
                              void* d_out, int out_size, void* d_ws, size_t ws_size,
                              hipStream_t stream) {
  const float* adjs            = (const float*)d_in[0];
  const float* feature         = (const float*)d_in[1];
  const int*   idxs            = (const int*)d_in[2];
  const float* adjs_hidden     = (const float*)d_in[3];
  const float* features_hidden = (const float*)d_in[4];
  float* out = (float*)d_out;
  float* ws  = (float*)d_ws;

  const int B = in_sizes[0] / (SS*SS);
  const int N = in_sizes[1] / DIN;

  hipLaunchKernelGGL(hidden_prep, dim3(1), dim3(256), 0, stream,
                     adjs_hidden, features_hidden, ws);
  const int nblk = (B + BT - 1) / BT;
  hipLaunchKernelGGL(kc_main, dim3(nblk), dim3(256), 0, stream,
                     adjs, feature, idxs, ws, out, B, N);
}

// Round 5
// 138.565 us; speedup vs baseline: 17.0220x; 17.0220x over previous
//
#include <hip/hip_runtime.h>
#include <math.h>

#define NF 8
#define SS 5
#define DIN 64
#define KSTEP 3
#define BT 32
#define FH_PAD 68             // padded row (bank spread, 16B-aligned rows)
#define FSTR (SS*FH_PAD)      // 340 (340%32=20 -> 8 distinct start banks per f)
#define HOPSTR (NF*FSTR)      // 2720
#define NS_OFF (KSTEP*HOPSTR) // ws: nsqh [3][8][5] after fh

// exp(-(sqf+sqh-2cr)/3.2) = 2^(CC*cr - CS*sqf - CS*sqh)
#define CS 0.45084219902780109f
#define CC 0.90168439805560218f

__device__ __forceinline__ float fexp2(float x) {
#if __has_builtin(__builtin_amdgcn_exp2f)
  return __builtin_amdgcn_exp2f(x);
#else
  return exp2f(x);
#endif
}

__global__ __launch_bounds__(256) void hidden_prep(
    const float* __restrict__ adjs_hidden,
    const float* __restrict__ features_hidden,
    float* __restrict__ ws)
{
  __shared__ float Ah[NF][SS][SS];
  __shared__ float buf[2][NF][SS][DIN];
  const int t = threadIdx.x;

  if (t < NF*SS*SS) ((float*)Ah)[t] = 0.0f;
  for (int i = t; i < NF*SS*DIN; i += 256) ((float*)buf[0])[i] = features_hidden[i];
  __syncthreads();
  if (t < NF*10) {
    const int iu0[10] = {0,0,0,0,1,1,1,2,2,3};
    const int iu1[10] = {1,2,3,4,2,3,4,3,4,4};
    int f = t / 10, k = t % 10;
    float sg = 1.0f / (1.0f + expf(-adjs_hidden[t]));
    Ah[f][iu0[k]][iu1[k]] = sg;
    Ah[f][iu1[k]][iu0[k]] = sg;
  }
  __syncthreads();

  int cur = 0;
  for (int h = 0; h < KSTEP; ++h) {
    // padded fh for this hop: ws[h*HOPSTR + f*FSTR + s*FH_PAD + d]
    for (int i = t; i < NF*SS*DIN; i += 256) {
      int f = i / (SS*DIN), s = (i / DIN) % SS, d = i % DIN;
      ws[h*HOPSTR + f*FSTR + s*FH_PAD + d] = buf[cur][f][s][d];
    }
    // negated, pre-scaled sq_h
    if (t < NF*SS) {
      float acc = 0.0f;
      int f = t / SS, s = t % SS;
      for (int d = 0; d < DIN; ++d) { float v = buf[cur][f][s][d]; acc = fmaf(v, v, acc); }
      ws[NS_OFF + h*NF*SS + t] = -acc * CS;
    }
    if (h + 1 < KSTEP) {
      __syncthreads();
      for (int i = t; i < NF*SS*DIN; i += 256) {
        int f = i / (SS*DIN), s = (i / DIN) % SS, d = i % DIN;
        float acc = 0.0f;
        for (int j = 0; j < SS; ++j) acc = fmaf(Ah[f][s][j], buf[cur][f][j][d], acc);
        buf[cur^1][f][s][d] = acc;
      }
      __syncthreads();
      cur ^= 1;
    }
  }
}

// Round-2 memory design (all bulk state in LDS, low VGPR) + exactly ONE
// __syncthreads (fh staging). Every other LDS dependency is octet-local:
// 8 consecutive lanes share one b -> same wave -> program order suffices.
__global__ __launch_bounds__(256, 2) void kc_main(
    const float* __restrict__ adjs,
    const float* __restrict__ feature,
    const int* __restrict__ idxs,
    const float* __restrict__ ws,
    float* __restrict__ out,
    int B, int N)
{
  __shared__ float fh[KSTEP*HOPSTR];     // 32640 B, conflict-free padded
  __shared__ float nsqh[KSTEP*NF*SS];    // 480 B
  __shared__ float fS[BT][SS][FH_PAD];   // 43520 B
  __shared__ float adjS[BT][SS*SS];      // 3200 B
  __shared__ float sqfS[BT][8];          // 1024 B   -> ~78 KB, 2 blocks/CU

  const int t   = threadIdx.x;
  const int b_i = t >> 3;   // 0..31 (octet = one b)
  const int f_  = t & 7;    // filter / d-slice owner
  const int bg  = blockIdx.x * BT + b_i;
  const bool valid = bg < B;

  // --- cooperative fh + nsqh staging (cross-wave -> the one barrier) ---
  for (int i = t; i < KSTEP*HOPSTR; i += 256) fh[i] = ws[i];
  for (int i = t; i < KSTEP*NF*SS; i += 256) nsqh[i] = ws[NS_OFF + i];

  // --- adj into LDS (octet-local writes) ---
  #pragma unroll
  for (int k = f_; k < SS*SS; k += 8)
    adjS[b_i][k] = valid ? adjs[(size_t)bg*(SS*SS) + k] : 0.0f;

  // --- gather: thread fetches d-columns [8f_, 8f_+8) of its b into fS ---
  #pragma unroll
  for (int m = 0; m < SS; ++m) {
    int id = valid ? idxs[bg*SS + m] : -1;
    #pragma unroll
    for (int h2 = 0; h2 < 2; ++h2) {
      float4 v = make_float4(0.f, 0.f, 0.f, 0.f);
      if ((unsigned)id < (unsigned)N)
        v = reinterpret_cast<const float4*>(feature)[(size_t)id*16 + f_*2 + h2];
      *reinterpret_cast<float4*>(&fS[b_i][m][f_*8 + h2*4]) = v;
    }
  }

  __syncthreads();  // fh/nsqh ready (fS/adjS are octet-local)

  float total[SS][SS];
  #pragma unroll
  for (int m = 0; m < SS; ++m)
    #pragma unroll
    for (int s = 0; s < SS; ++s) total[m][s] = 0.0f;

  for (int hop = 0; hop < KSTEP; ++hop) {
    if (hop) {
      // f <- adjs @ f : thread reads+writes only its own d-columns (octet-local)
      const int dbase = f_ * 8;
      float fo[SS][8];
      #pragma unroll
      for (int j = 0; j < SS; ++j)
        #pragma unroll
        for (int h2 = 0; h2 < 2; ++h2) {
          float4 v = *reinterpret_cast<const float4*>(&fS[b_i][j][dbase + h2*4]);
          fo[j][h2*4+0] = v.x; fo[j][h2*4+1] = v.y;
          fo[j][h2*4+2] = v.z; fo[j][h2*4+3] = v.w;
        }
      #pragma unroll
      for (int m = 0; m < SS; ++m) {
        float fn[8];
        #pragma unroll
        for (int dd = 0; dd < 8; ++dd) fn[dd] = 0.0f;
        #pragma unroll
        for (int j = 0; j < SS; ++j) {
          float a = adjS[b_i][m*SS + j];
          #pragma unroll
          for (int dd = 0; dd < 8; ++dd) fn[dd] = fmaf(a, fo[j][dd], fn[dd]);
        }
        #pragma unroll
        for (int h2 = 0; h2 < 2; ++h2) {
          float4 v = make_float4(fn[h2*4+0], fn[h2*4+1], fn[h2*4+2], fn[h2*4+3]);
          *reinterpret_cast<float4*>(&fS[b_i][m][dbase + h2*4]) = v;
        }
      }
      // no barrier: octet-local, same wave
    }

    // shared ||f||^2 (pre-scaled by CS): lanes f_<5 do one row each
    if (f_ < SS) {
      float acc = 0.0f;
      const float* fr = &fS[b_i][f_][0];
      #pragma unroll
      for (int d4 = 0; d4 < 16; ++d4) {
        float4 v = *reinterpret_cast<const float4*>(&fr[d4*4]);
        acc = fmaf(v.x, v.x, acc);
        acc = fmaf(v.y, v.y, acc);
        acc = fmaf(v.z, v.z, acc);
        acc = fmaf(v.w, v.w, acc);
      }
      sqfS[b_i][f_] = acc * CS;
    }
    // no barrier: octet-local, same wave

    float cr[SS][SS];
    #pragma unroll
    for (int m = 0; m < SS; ++m)
      #pragma unroll
      for (int s = 0; s < SS; ++s) cr[m][s] = 0.0f;

    const float* fhh = &fh[hop*HOPSTR + f_*FSTR];
    #pragma unroll
    for (int d4 = 0; d4 < 16; ++d4) {
      float4 fv[SS], hv[SS];
      #pragma unroll
      for (int m = 0; m < SS; ++m)
        fv[m] = *reinterpret_cast<const float4*>(&fS[b_i][m][d4*4]);
      #pragma unroll
      for (int s = 0; s < SS; ++s)
        hv[s] = *reinterpret_cast<const float4*>(&fhh[s*FH_PAD + d4*4]);
      #pragma unroll
      for (int m = 0; m < SS; ++m)
        #pragma unroll
        for (int s = 0; s < SS; ++s) {
          cr[m][s] = fmaf(fv[m].x, hv[s].x, cr[m][s]);
          cr[m][s] = fmaf(fv[m].y, hv[s].y, cr[m][s]);
          cr[m][s] = fmaf(fv[m].z, hv[s].z, cr[m][s]);
          cr[m][s] = fmaf(fv[m].w, hv[s].w, cr[m][s]);
        }
    }

    float sqf2[SS], nh[SS];
    #pragma unroll
    for (int m = 0; m < SS; ++m) sqf2[m] = sqfS[b_i][m];
    #pragma unroll
    for (int s = 0; s < SS; ++s) nh[s] = nsqh[hop*NF*SS + f_*SS + s];
    #pragma unroll
    for (int m = 0; m < SS; ++m)
      #pragma unroll
      for (int s = 0; s < SS; ++s) {
        float arg = fmaf(CC, cr[m][s], nh[s] - sqf2[m]);  // <= 0 always
        total[m][s] += fexp2(arg);
      }
  }

  // greedy matching: row 0 -> col 0; rows 1..4 argmax over untaken cols
  float res = total[0][0];
  int taken = 1;
  #pragma unroll
  for (int r = 1; r < SS; ++r) {
    float best = -2.0f; int bi = 0;
    #pragma unroll
    for (int s = 0; s < SS; ++s) {
      float sc = ((taken >> s) & 1) ? -1.0f : total[r][s];
      if (sc > best) { best = sc; bi = s; }
    }
    res += best;
    taken |= (1 << bi);
  }
  if (valid) out[(size_t)bg*NF + f_] = res;
}

extern "C" void kernel_launch(void* const* d_in, const int* in_sizes, int n_in,
                              void* d_out, int out_size, void* d_ws, size_t ws_size,
                              hipStream_t stream) {
  const float* adjs            = (const float*)d_in[0];
  const float* feature         = (const float*)d_in[1];
  const int*   idxs            = (const int*)d_in[2];
  const float* adjs_hidden     = (const float*)d_in[3];
  const float* features_hidden = (const float*)d_in[4];
  float* out = (float*)d_out;
  float* ws  = (float*)d_ws;

  const int B = in_sizes[0] / (SS*SS);
  const int N = in_sizes[1] / DIN;

  hipLaunchKernelGGL(hidden_prep, dim3(1), dim3(256), 0, stream,
                     adjs_hidden, features_hidden, ws);
  const int nblk = (B + BT - 1) / BT;
  hipLaunchKernelGGL(kc_main, dim3(nblk), dim3(256), 0, stream,
                     adjs, feature, idxs, ws, out, B, N);
}